// Round 7
// baseline (74.690 us; speedup 1.0000x reference)
//
#include <hip/hip_runtime.h>

// labels[b,l,c] = argmin_q ( LN(t)[b,l,c] - LN(code_book)[c,q] )
//              = argmax_q LN(code_book)[c,q]        (tn constant along q)
//              = argmax_q code_book[c,q]            (global-scalar LN is monotone)
// => output is a 256-entry per-c label vector broadcast over (B, L).
//
// v7: single dispatch (saves the ~5 µs second-launch overhead measured
// v1->v6), keeping v6's coalesced access. Per block: 4 lanes per row,
// 16 rows per wave-load instruction (16 cache lines/instr, vs v1's 64-line
// gather), 64-candidate in-lane chain + 2-step shfl_xor group reduce under
// the total order (value desc, index asc) — associative+commutative, exact
// first-index tie-break (HW-verified absmax=0 in v5/v6). Each block reads
// the 256 KB codebook exactly once (no intra-block redundancy), computes
// all 256 labels in 4 outer iterations, then broadcast-stores its output
// slice. Outer loop NOT unrolled (v2 lesson: full unroll -> VGPR cliff).

#define C_DIM 256
#define Q_DIM 256
#define OUT_INT4 (4 * 512 * 256 / 4)   // B*L*C / 4 = 131072 int4 stores
#define NBLOCKS 256

__global__ __launch_bounds__(256) void rpq_fused(const float* __restrict__ cb,
                                                 int* __restrict__ out) {
    __shared__ int s[C_DIM];
    const int tid  = threadIdx.x;
    const int lane = tid & 63;
    const int wave = tid >> 6;
    const int p    = lane & 3;    // lane within 4-lane row group
    const int rloc = lane >> 2;   // which of the wave's 16 rows

#pragma unroll 1
    for (int i = 0; i < 4; ++i) {
        const int row = i * 64 + wave * 16 + rloc;
        const float4* rp = (const float4*)(cb + row * Q_DIM) + p;
        float b  = -3.4e38f;
        int  idx = 0;
        // Lane p scans float4s p, p+4, ..., p+60 of its row: indices are
        // strictly ascending in j, so strict '>' keeps the earliest index.
#pragma unroll
        for (int j = 0; j < 16; ++j) {
            float4 v = rp[j * 4];
            int q = (p + j * 4) * 4;
            if (v.x > b) { b = v.x; idx = q; }
            if (v.y > b) { b = v.y; idx = q + 1; }
            if (v.z > b) { b = v.z; idx = q + 2; }
            if (v.w > b) { b = v.w; idx = q + 3; }
        }
        // Reduce across the 4-lane group (partners l^1, l^2 share the row):
        // take partner's candidate iff larger value, or equal and smaller idx.
#pragma unroll
        for (int off = 1; off < 4; off <<= 1) {
            float ob = __shfl_xor(b, off, 64);
            int   oi = __shfl_xor(idx, off, 64);
            if (ob > b || (ob == b && oi < idx)) { b = ob; idx = oi; }
        }
        if (p == 0) s[row] = idx;
    }
    __syncthreads();

    // Each thread's int4 payload is invariant across its grid-stride stores:
    // for i = blk*256 + tid + k*65536, (4i) mod 256 == 4*(tid & 63).
    const int base = lane * 4;
    const int4 v = make_int4(s[base], s[base + 1], s[base + 2], s[base + 3]);
    int4* o4 = (int4*)out;
    for (int i = blockIdx.x * 256 + tid; i < OUT_INT4; i += NBLOCKS * 256) {
        o4[i] = v;
    }
}

extern "C" void kernel_launch(void* const* d_in, const int* in_sizes, int n_in,
                              void* d_out, int out_size, void* d_ws, size_t ws_size,
                              hipStream_t stream) {
    // inputs: 0=input_values (B,L,D) f32, 1=W (Q,D) f32, 2=code_book (C,Q) f32, 3=raw_signal
    const float* code_book = (const float*)d_in[2];
    int* out = (int*)d_out;
    rpq_fused<<<NBLOCKS, 256, 0, stream>>>(code_book, out);
}